// Round 9
// baseline (200.155 us; speedup 1.0000x reference)
//
#include <hip/hip_runtime.h>
#include <hip/hip_bf16.h>
#include <cstdint>
#include <cstddef>

#define B_SZ 4
#define T_SZ 1024
#define N_SZ 1024
#define HID 1024
#define NHEADS 16
#define DHEAD 64

typedef __bf16 bf16x8 __attribute__((ext_vector_type(8)));
typedef __bf16 bf16x4 __attribute__((ext_vector_type(4)));
typedef float floatx4 __attribute__((ext_vector_type(4)));

// LDS leading dims MUST be multiples of 8 bf16 (16B): rows stay 16B-aligned so
// ds_read_b128/ds_write_b64 are emitted (R6 lesson: 66/68 broke b128 -> -21%).
#define LKV 72
#define LP  72

// log2(e)/sqrt(64), folded into Q at load; shift-free exp2-domain softmax
#define SM_SCALE_LOG2E 0.18033688011112042f

// ---------------------------------------------------------------------------
// Fused QKV GEMM v2: fp32 inputs (x/enc/W read directly -- cvt5 kernel is
// GONE), register-staged software pipeline (attn-v4 pattern):
//   per K-iter: issue 16 float4 global loads (next tile) -> 32 MFMA on current
//   LDS buffer -> cvt to bf16 + 8 ds_write_b128 into other buffer -> ONE
//   barrier. No vmcnt(0)-drain-before-compute stall (R8: that drain made the
//   m97 structure latency-bound at K=1024: MfmaUtil 17%, VALU 22%, HBM 13%).
// LDS [2][128x64] x2 = 64KB -> 2 blocks/CU. XOR swizzle in LDS addresses only
// (global reads contiguous; frag reads 2-way free, R8 measured 0 conflicts).
// grid (8,32,3): bn, bm, z-mux {x*Wq+bq, enc*Wk+bk, enc*Wv+bv}.
// ---------------------------------------------------------------------------
__global__ __launch_bounds__(256)
void gemm3_f32_pipe(const float* __restrict__ x, const float* __restrict__ enc,
                    const float* __restrict__ wq, const float* __restrict__ wk,
                    const float* __restrict__ wv,
                    const float* __restrict__ bq, const float* __restrict__ bk,
                    const float* __restrict__ bv,
                    __bf16* __restrict__ qo, __bf16* __restrict__ ko,
                    __bf16* __restrict__ vo)
{
    constexpr int K = HID;
    __shared__ __align__(16) __bf16 As[2][128 * 64];
    __shared__ __align__(16) __bf16 Bs[2][128 * 64];

    const float* A; const float* W; const float* bias; __bf16* C;
    if (blockIdx.z == 0)      { A = x;   W = wq; bias = bq; C = qo; }
    else if (blockIdx.z == 1) { A = enc; W = wk; bias = bk; C = ko; }
    else                      { A = enc; W = wv; bias = bv; C = vo; }

    const int tid  = threadIdx.x;
    const int wave = tid >> 6;
    const int lane = tid & 63;
    const int l15  = lane & 15;
    const int quad = lane >> 4;
    const int bm = blockIdx.y * 128;
    const int bn = blockIdx.x * 128;
    const int wm = (wave >> 1) * 64;
    const int wn = (wave & 1) * 64;

    floatx4 acc[4][4];
#pragma unroll
    for (int i = 0; i < 4; ++i)
#pragma unroll
        for (int j = 0; j < 4; ++j)
            acc[i][j] = (floatx4)(0.0f);

    // staging geometry: thread covers rows sr+32p (p=0..3), 8 consecutive
    // source floats at col (tid&7)*8; dest LDS chunk = (tid&7)^(sr&7)
    // (32p preserves r&7). Layout: LDS[r][c'] with c' = c ^ (r&7).
    const int sr     = tid >> 3;            // 0..31
    const int scol   = (tid & 7) * 8;       // source col (floats)
    const int dchunk = (tid & 7) ^ (sr & 7);
    const size_t arow = (size_t)(bm + sr) * K + scol;
    const size_t wrow = (size_t)(bn + sr) * K + scol;

    // ---- prologue: stage tile 0 into buffer 0 ----
    {
#pragma unroll
        for (int p = 0; p < 4; ++p) {
            const float4 a0 = *(const float4*)(A + arow + (size_t)p * 32 * K);
            const float4 a1 = *(const float4*)(A + arow + (size_t)p * 32 * K + 4);
            const float4 w0 = *(const float4*)(W + wrow + (size_t)p * 32 * K);
            const float4 w1 = *(const float4*)(W + wrow + (size_t)p * 32 * K + 4);
            bf16x8 av, wv8;
            av[0] = (__bf16)a0.x; av[1] = (__bf16)a0.y; av[2] = (__bf16)a0.z; av[3] = (__bf16)a0.w;
            av[4] = (__bf16)a1.x; av[5] = (__bf16)a1.y; av[6] = (__bf16)a1.z; av[7] = (__bf16)a1.w;
            wv8[0] = (__bf16)w0.x; wv8[1] = (__bf16)w0.y; wv8[2] = (__bf16)w0.z; wv8[3] = (__bf16)w0.w;
            wv8[4] = (__bf16)w1.x; wv8[5] = (__bf16)w1.y; wv8[6] = (__bf16)w1.z; wv8[7] = (__bf16)w1.w;
            *(bf16x8*)(&As[0][(sr + p * 32) * 64 + dchunk * 8]) = av;
            *(bf16x8*)(&Bs[0][(sr + p * 32) * 64 + dchunk * 8]) = wv8;
        }
    }
    __syncthreads();

    for (int it = 0; it < 16; ++it) {
        const int bi = it & 1;
        const bool pf = (it + 1 < 16);

        // ---- prefetch next K-slab into registers (in flight across MFMA) ----
        float4 ra0[4], ra1[4], rw0[4], rw1[4];
        if (pf) {
            const int k0 = (it + 1) * 64;
#pragma unroll
            for (int p = 0; p < 4; ++p) {
                ra0[p] = *(const float4*)(A + arow + (size_t)p * 32 * K + k0);
                ra1[p] = *(const float4*)(A + arow + (size_t)p * 32 * K + k0 + 4);
                rw0[p] = *(const float4*)(W + wrow + (size_t)p * 32 * K + k0);
                rw1[p] = *(const float4*)(W + wrow + (size_t)p * 32 * K + k0 + 4);
            }
        }

        // ---- compute on buffer bi: 32 MFMA ----
#pragma unroll
        for (int kk = 0; kk < 2; ++kk) {
            const int ch = kk * 4 + quad;
            bf16x8 af[4], bfr[4];
#pragma unroll
            for (int i = 0; i < 4; ++i) {
                const int ra_ = wm + i * 16 + l15;
                const int rb_ = wn + i * 16 + l15;
                af[i]  = *(const bf16x8*)((const char*)&As[bi][0] + ra_ * 128 + ((ch ^ (ra_ & 7)) << 4));
                bfr[i] = *(const bf16x8*)((const char*)&Bs[bi][0] + rb_ * 128 + ((ch ^ (rb_ & 7)) << 4));
            }
#pragma unroll
            for (int mi = 0; mi < 4; ++mi)
#pragma unroll
                for (int ni = 0; ni < 4; ++ni)
                    acc[mi][ni] = __builtin_amdgcn_mfma_f32_16x16x32_bf16(
                        af[mi], bfr[ni], acc[mi][ni], 0, 0, 0);
        }

        // ---- cvt + write prefetched slab into the other buffer ----
        if (pf) {
            const int wb = bi ^ 1;
#pragma unroll
            for (int p = 0; p < 4; ++p) {
                bf16x8 av, wv8;
                av[0] = (__bf16)ra0[p].x; av[1] = (__bf16)ra0[p].y;
                av[2] = (__bf16)ra0[p].z; av[3] = (__bf16)ra0[p].w;
                av[4] = (__bf16)ra1[p].x; av[5] = (__bf16)ra1[p].y;
                av[6] = (__bf16)ra1[p].z; av[7] = (__bf16)ra1[p].w;
                wv8[0] = (__bf16)rw0[p].x; wv8[1] = (__bf16)rw0[p].y;
                wv8[2] = (__bf16)rw0[p].z; wv8[3] = (__bf16)rw0[p].w;
                wv8[4] = (__bf16)rw1[p].x; wv8[5] = (__bf16)rw1[p].y;
                wv8[6] = (__bf16)rw1[p].z; wv8[7] = (__bf16)rw1[p].w;
                *(bf16x8*)(&As[wb][(sr + p * 32) * 64 + dchunk * 8]) = av;
                *(bf16x8*)(&Bs[wb][(sr + p * 32) * 64 + dchunk * 8]) = wv8;
            }
        }
        __syncthreads();   // single barrier per K-iter
    }

    // C/D layout: col = lane&15, row = (lane>>4)*4 + reg   [m89/m91-verified]
    const int crow0 = bm + wm + quad * 4;
    const int ccol0 = bn + wn + l15;
#pragma unroll
    for (int ni = 0; ni < 4; ++ni) {
        const int n = ccol0 + ni * 16;
        const float bias_f = bias[n];
#pragma unroll
        for (int mi = 0; mi < 4; ++mi) {
#pragma unroll
            for (int r = 0; r < 4; ++r) {
                const int m = crow0 + mi * 16 + r;
                C[(size_t)m * HID + n] = (__bf16)(acc[mi][ni][r] + bias_f);
            }
        }
    }
}

// ---------------------------------------------------------------------------
// Flash attention v4 (unchanged from R7/R8; ~40 us): transposed-S data flow,
// shift-free exp2 softmax, double-buffered K/V, one barrier/tile, balanced
// block pairing. grid = 512; block = 256.
// ---------------------------------------------------------------------------
__global__ __launch_bounds__(256)
void attn_flash_mfma_v4(const __bf16* __restrict__ q,
                        const __bf16* __restrict__ k,
                        const __bf16* __restrict__ v,
                        float* __restrict__ out)
{
    __shared__ __align__(16) __bf16 Ks[2][64 * LKV];    // [n][d]
    __shared__ __align__(16) __bf16 Vt[2][64 * LKV];    // [d][n]
    __shared__ __align__(16) __bf16 Ps[4][32 * LP];     // per-wave P [m][n]

    const int tid  = threadIdx.x;
    const int wave = tid >> 6;
    const int lane = tid & 63;
    const int l15  = lane & 15;
    const int quad = lane >> 4;

    const int bx = blockIdx.x;           // 0..511
    const int jj = bx & 7;
    const int bt = ((bx >> 8) & 1) ? jj : 7 - jj;   // pair-balanced LJF
    const int bh = bx >> 3;              // 0..63
    const int h  = bh & (NHEADS - 1);
    const int b  = bh >> 4;
    const int t0 = bt * 128;

    const __bf16* kbase = k + (size_t)b * N_SZ * HID + h * DHEAD;
    const __bf16* vbase = v + (size_t)b * N_SZ * HID + h * DHEAD;

    // ---- Q rows to registers (B-frag of S^T), pre-scaled ----
    bf16x8 qf[2][2];
    {
        const __bf16* qb = q + (size_t)(b * T_SZ + t0 + wave * 32) * HID + h * DHEAD;
#pragma unroll
        for (int g = 0; g < 2; ++g)
#pragma unroll
            for (int kk = 0; kk < 2; ++kk) {
                const bf16x8 raw = *(const bf16x8*)(qb + (size_t)(g * 16 + l15) * HID
                                                    + kk * 32 + quad * 8);
#pragma unroll
                for (int j = 0; j < 8; ++j)
                    qf[g][kk][j] = (__bf16)((float)raw[j] * SM_SCALE_LOG2E);
            }
    }

    const int kr = tid >> 3;
    const int kc = (tid & 7) * 8;
    const int vn = tid & 63;
    const int vd = (tid >> 6) * 8;

#pragma unroll
    for (int p = 0; p < 2; ++p) {
        *(bf16x8*)(&Ks[0][(kr + p * 32) * LKV + kc]) =
            *(const bf16x8*)(kbase + (size_t)(kr + p * 32) * HID + kc);
        const bf16x8 vv = *(const bf16x8*)(vbase + (size_t)vn * HID + vd + p * 32);
#pragma unroll
        for (int j = 0; j < 8; ++j)
            Vt[0][(vd + p * 32 + j) * LKV + vn] = vv[j];
    }
    __syncthreads();

    float lsum[2] = {0.f, 0.f};
    floatx4 oacc[2][4];
#pragma unroll
    for (int g = 0; g < 2; ++g)
#pragma unroll
        for (int nd = 0; nd < 4; ++nd) oacc[g][nd] = (floatx4)(0.0f);

    __bf16* pw = &Ps[wave][0];
    const int ntiles = 2 * bt + 2;

    for (int it = 0; it < ntiles; ++it) {
        const int bi = it & 1;
        const int n0 = it * 64;

        bf16x8 nk0, nk1, nv0, nv1;
        const bool pf = (it + 1 < ntiles);
        if (pf) {
            const int nn0 = n0 + 64;
            nk0 = *(const bf16x8*)(kbase + (size_t)(nn0 + kr) * HID + kc);
            nk1 = *(const bf16x8*)(kbase + (size_t)(nn0 + kr + 32) * HID + kc);
            nv0 = *(const bf16x8*)(vbase + (size_t)(nn0 + vn) * HID + vd);
            nv1 = *(const bf16x8*)(vbase + (size_t)(nn0 + vn) * HID + vd + 32);
        }

        // ---- S^T = K @ Q^T : C/D col=m(l15), row=n(quad*4+r) ----
        floatx4 st[2][4];
#pragma unroll
        for (int g = 0; g < 2; ++g)
#pragma unroll
            for (int ni = 0; ni < 4; ++ni) st[g][ni] = (floatx4)(0.0f);
        const __bf16* ksb = &Ks[bi][0];
#pragma unroll
        for (int kk = 0; kk < 2; ++kk) {
            const int ko = kk * 32 + quad * 8;
#pragma unroll
            for (int ni = 0; ni < 4; ++ni) {
                const bf16x8 af = *(const bf16x8*)(ksb + (ni * 16 + l15) * LKV + ko);
                st[0][ni] = __builtin_amdgcn_mfma_f32_16x16x32_bf16(af, qf[0][kk], st[0][ni], 0, 0, 0);
                st[1][ni] = __builtin_amdgcn_mfma_f32_16x16x32_bf16(af, qf[1][kk], st[1][ni], 0, 0, 0);
            }
        }

        // ---- shift-free softmax; packed b64 P-writes; lane-local lsum ----
        const bool msk = (it >= 2 * bt);
#pragma unroll
        for (int g = 0; g < 2; ++g) {
            const int tq = t0 + wave * 32 + g * 16 + l15;
#pragma unroll
            for (int ni = 0; ni < 4; ++ni) {
                bf16x4 pk;
#pragma unroll
                for (int r = 0; r < 4; ++r) {
                    float p = exp2f(st[g][ni][r]);
                    if (msk) {
                        const int nn = n0 + ni * 16 + quad * 4 + r;
                        p = (nn > tq) ? 0.f : p;
                    }
                    lsum[g] += p;
                    pk[r] = (__bf16)p;
                }
                *(bf16x4*)(pw + (g * 16 + l15) * LP + ni * 16 + quad * 4) = pk;
            }
        }

        // ---- O^T += Vt @ P : C/D col=m(l15), row=d(quad*4+r) ----
        const __bf16* vtb = &Vt[bi][0];
#pragma unroll
        for (int kk = 0; kk < 2; ++kk) {
            const int ko = kk * 32 + quad * 8;
            const bf16x8 bp0 = *(const bf16x8*)(pw + l15 * LP + ko);
            const bf16x8 bp1 = *(const bf16x8*)(pw + (16 + l15) * LP + ko);
#pragma unroll
            for (int nd = 0; nd < 4; ++nd) {
                const bf16x8 av = *(const bf16x8*)(vtb + (nd * 16 + l15) * LKV + ko);
                oacc[0][nd] = __builtin_amdgcn_mfma_f32_16x16x32_bf16(av, bp0, oacc[0][nd], 0, 0, 0);
                oacc[1][nd] = __builtin_amdgcn_mfma_f32_16x16x32_bf16(av, bp1, oacc[1][nd], 0, 0, 0);
            }
        }

        if (pf) {
            const int wb = bi ^ 1;
            *(bf16x8*)(&Ks[wb][kr * LKV + kc]) = nk0;
            *(bf16x8*)(&Ks[wb][(kr + 32) * LKV + kc]) = nk1;
#pragma unroll
            for (int j = 0; j < 8; ++j) {
                Vt[wb][(vd + j) * LKV + vn] = nv0[j];
                Vt[wb][(vd + 32 + j) * LKV + vn] = nv1[j];
            }
        }
        __syncthreads();
    }

    // ---- epilogue ----
#pragma unroll
    for (int g = 0; g < 2; ++g) {
        lsum[g] += __shfl_xor(lsum[g], 16, 64);
        lsum[g] += __shfl_xor(lsum[g], 32, 64);
    }
#pragma unroll
    for (int g = 0; g < 2; ++g) {
        const float invl = 1.0f / lsum[g];
        const int trow = t0 + wave * 32 + g * 16 + l15;
        float* ob = out + (size_t)(b * T_SZ + trow) * HID + h * DHEAD + quad * 4;
#pragma unroll
        for (int nd = 0; nd < 4; ++nd) {
            float4 o4;
            o4.x = oacc[g][nd][0] * invl;
            o4.y = oacc[g][nd][1] * invl;
            o4.z = oacc[g][nd][2] * invl;
            o4.w = oacc[g][nd][3] * invl;
            *(float4*)(ob + nd * 16) = o4;
        }
    }
}

extern "C" void kernel_launch(void* const* d_in, const int* in_sizes, int n_in,
                              void* d_out, int out_size, void* d_ws, size_t ws_size,
                              hipStream_t stream) {
    const float* x   = (const float*)d_in[0];
    const float* enc = (const float*)d_in[1];
    const float* Wq  = (const float*)d_in[2];
    const float* bq  = (const float*)d_in[3];
    const float* Wk  = (const float*)d_in[4];
    const float* bk  = (const float*)d_in[5];
    const float* Wv  = (const float*)d_in[6];
    const float* bv  = (const float*)d_in[7];
    float* out = (float*)d_out;

    char* ws = (char*)d_ws;
    const size_t MiB = 1024 * 1024;
    __bf16* q_ws = (__bf16*)(ws);
    __bf16* k_ws = (__bf16*)(ws + 8 * MiB);
    __bf16* v_ws = (__bf16*)(ws + 16 * MiB);

    const dim3 blk(256);
    gemm3_f32_pipe<<<dim3(8, 32, 3), blk, 0, stream>>>(
        x, enc, Wq, Wk, Wv, bq, bk, bv, q_ws, k_ws, v_ws);

    attn_flash_mfma_v4<<<dim3(512), blk, 0, stream>>>(q_ws, k_ws, v_ws, out);
}

// Round 10
// 174.897 us; speedup vs baseline: 1.1444x; 1.1444x over previous
//
#include <hip/hip_runtime.h>
#include <hip/hip_bf16.h>
#include <cstdint>
#include <cstddef>

#define B_SZ 4
#define T_SZ 1024
#define N_SZ 1024
#define HID 1024
#define NHEADS 16
#define DHEAD 64

typedef __bf16 bf16x8 __attribute__((ext_vector_type(8)));
typedef __bf16 bf16x4 __attribute__((ext_vector_type(4)));
typedef float floatx4 __attribute__((ext_vector_type(4)));

// LDS leading dims MUST be multiples of 8 bf16 (16B): rows stay 16B-aligned so
// ds_read_b128/ds_write_b64 are emitted (R6 lesson: 66/68 broke b128 -> -21%).
#define LKV 72
#define LP  72

// log2(e)/sqrt(64), folded into Q at load; shift-free exp2-domain softmax
#define SM_SCALE_LOG2E 0.18033688011112042f

// ---------------------------------------------------------------------------
// Fused QKV GEMM v3 (R10): fp32 inputs read directly (no cvt5 kernel),
// combining the two HW-verified wins:
//   - R8 XCD remap: all 8 bn-blocks of one (z,bm) on one XCD -> A-slice
//     fetched once per XCD (R8 measured FETCH 101->29.8 MB on bf16).
//   - R9 register prefetch, but issued a FULL compute phase ahead of the
//     barrier that drains it: loads get ~400cyc of MFMA in flight, so the
//     compiler's vmcnt(0)-before-s_barrier costs ~nothing (R8's structure
//     issued loads right before the drain -> latency-bound, MfmaUtil 17%).
//   - single 32KB LDS pair (not R9's 64KB dbuf) -> 3 blocks/CU, all 768
//     blocks co-resident (R9 ran 1.5 scheduling rounds at 2/CU).
// Per K-iter: [issue 16 float4 loads for k+1] [32 MFMA on LDS] [barrier]
//             [cvt+write LDS] [barrier].
// XOR swizzle in LDS addresses (R8: 0 bank conflicts).
// ---------------------------------------------------------------------------
__global__ __launch_bounds__(256, 3)
void gemm3_f32_swz(const float* __restrict__ x, const float* __restrict__ enc,
                   const float* __restrict__ wq, const float* __restrict__ wk,
                   const float* __restrict__ wv,
                   const float* __restrict__ bq, const float* __restrict__ bk,
                   const float* __restrict__ bv,
                   __bf16* __restrict__ qo, __bf16* __restrict__ ko,
                   __bf16* __restrict__ vo)
{
    constexpr int K = HID;
    __shared__ __align__(16) __bf16 As[128 * 64];
    __shared__ __align__(16) __bf16 Bs[128 * 64];

    // R8 XCD-aware remap (dispatch round-robins blocks over 8 XCDs):
    const int bid  = blockIdx.x;          // 0..767
    const int xcd  = bid & 7;
    const int slot = bid >> 3;            // 0..95
    const int bn   = (slot & 7) * 128;
    const int pair = xcd * 12 + (slot >> 3);   // 0..95, bijective
    const int z    = pair >> 5;           // 0..2
    const int bm   = (pair & 31) * 128;

    const float* A; const float* W; const float* bias; __bf16* C;
    if (z == 0)      { A = x;   W = wq; bias = bq; C = qo; }
    else if (z == 1) { A = enc; W = wk; bias = bk; C = ko; }
    else             { A = enc; W = wv; bias = bv; C = vo; }

    const int tid  = threadIdx.x;
    const int wave = tid >> 6;
    const int lane = tid & 63;
    const int l15  = lane & 15;
    const int quad = lane >> 4;
    const int wm = (wave >> 1) * 64;
    const int wn = (wave & 1) * 64;

    floatx4 acc[4][4];
#pragma unroll
    for (int i = 0; i < 4; ++i)
#pragma unroll
        for (int j = 0; j < 4; ++j)
            acc[i][j] = (floatx4)(0.0f);

    // staging geometry: thread covers rows sr+32p (p=0..3), 8 consecutive
    // source floats at col (tid&7)*8; dest LDS chunk = (tid&7)^(sr&7)
    // (32p preserves r&7). Layout: LDS[r][c'] = src[r][c' ^ (r&7)].
    const int sr     = tid >> 3;            // 0..31
    const int scol   = (tid & 7) * 8;       // source col (floats)
    const int dchunk = (tid & 7) ^ (sr & 7);
    const size_t arow = (size_t)(bm + sr) * K + scol;
    const size_t wrow = (size_t)(bn + sr) * K + scol;

    // ---- prologue: load + stage tile 0 ----
#pragma unroll
    for (int p = 0; p < 4; ++p) {
        const float4 a0 = *(const float4*)(A + arow + (size_t)p * 32 * K);
        const float4 a1 = *(const float4*)(A + arow + (size_t)p * 32 * K + 4);
        const float4 w0 = *(const float4*)(W + wrow + (size_t)p * 32 * K);
        const float4 w1 = *(const float4*)(W + wrow + (size_t)p * 32 * K + 4);
        bf16x8 av, wv8;
        av[0] = (__bf16)a0.x; av[1] = (__bf16)a0.y; av[2] = (__bf16)a0.z; av[3] = (__bf16)a0.w;
        av[4] = (__bf16)a1.x; av[5] = (__bf16)a1.y; av[6] = (__bf16)a1.z; av[7] = (__bf16)a1.w;
        wv8[0] = (__bf16)w0.x; wv8[1] = (__bf16)w0.y; wv8[2] = (__bf16)w0.z; wv8[3] = (__bf16)w0.w;
        wv8[4] = (__bf16)w1.x; wv8[5] = (__bf16)w1.y; wv8[6] = (__bf16)w1.z; wv8[7] = (__bf16)w1.w;
        *(bf16x8*)(&As[(sr + p * 32) * 64 + dchunk * 8]) = av;
        *(bf16x8*)(&Bs[(sr + p * 32) * 64 + dchunk * 8]) = wv8;
    }
    __syncthreads();

    for (int it = 0; it < 16; ++it) {
        const bool pf = (it + 1 < 16);

        // ---- prefetch next K-slab into registers (in flight across MFMA) ----
        float4 ra0[4], ra1[4], rw0[4], rw1[4];
        if (pf) {
            const int k0 = (it + 1) * 64;
#pragma unroll
            for (int p = 0; p < 4; ++p) {
                ra0[p] = *(const float4*)(A + arow + (size_t)p * 32 * K + k0);
                ra1[p] = *(const float4*)(A + arow + (size_t)p * 32 * K + k0 + 4);
                rw0[p] = *(const float4*)(W + wrow + (size_t)p * 32 * K + k0);
                rw1[p] = *(const float4*)(W + wrow + (size_t)p * 32 * K + k0 + 4);
            }
        }

        // ---- compute on current LDS: 32 MFMA (~400 cyc of load cover) ----
#pragma unroll
        for (int kk = 0; kk < 2; ++kk) {
            const int ch = kk * 4 + quad;
            bf16x8 af[4], bfr[4];
#pragma unroll
            for (int i = 0; i < 4; ++i) {
                const int ra_ = wm + i * 16 + l15;
                const int rb_ = wn + i * 16 + l15;
                af[i]  = *(const bf16x8*)((const char*)As + ra_ * 128 + ((ch ^ (ra_ & 7)) << 4));
                bfr[i] = *(const bf16x8*)((const char*)Bs + rb_ * 128 + ((ch ^ (rb_ & 7)) << 4));
            }
#pragma unroll
            for (int mi = 0; mi < 4; ++mi)
#pragma unroll
                for (int ni = 0; ni < 4; ++ni)
                    acc[mi][ni] = __builtin_amdgcn_mfma_f32_16x16x32_bf16(
                        af[mi], bfr[ni], acc[mi][ni], 0, 0, 0);
        }
        __syncthreads();   // all waves done reading LDS; prefetch mostly landed

        // ---- cvt + overwrite LDS with next tile ----
        if (pf) {
#pragma unroll
            for (int p = 0; p < 4; ++p) {
                bf16x8 av, wv8;
                av[0] = (__bf16)ra0[p].x; av[1] = (__bf16)ra0[p].y;
                av[2] = (__bf16)ra0[p].z; av[3] = (__bf16)ra0[p].w;
                av[4] = (__bf16)ra1[p].x; av[5] = (__bf16)ra1[p].y;
                av[6] = (__bf16)ra1[p].z; av[7] = (__bf16)ra1[p].w;
                wv8[0] = (__bf16)rw0[p].x; wv8[1] = (__bf16)rw0[p].y;
                wv8[2] = (__bf16)rw0[p].z; wv8[3] = (__bf16)rw0[p].w;
                wv8[4] = (__bf16)rw1[p].x; wv8[5] = (__bf16)rw1[p].y;
                wv8[6] = (__bf16)rw1[p].z; wv8[7] = (__bf16)rw1[p].w;
                *(bf16x8*)(&As[(sr + p * 32) * 64 + dchunk * 8]) = av;
                *(bf16x8*)(&Bs[(sr + p * 32) * 64 + dchunk * 8]) = wv8;
            }
            __syncthreads();
        }
    }

    // C/D layout: col = lane&15, row = (lane>>4)*4 + reg   [m89/m91-verified]
    const int crow0 = bm + wm + quad * 4;
    const int ccol0 = bn + wn + l15;
#pragma unroll
    for (int ni = 0; ni < 4; ++ni) {
        const int n = ccol0 + ni * 16;
        const float bias_f = bias[n];
#pragma unroll
        for (int mi = 0; mi < 4; ++mi) {
#pragma unroll
            for (int r = 0; r < 4; ++r) {
                const int m = crow0 + mi * 16 + r;
                C[(size_t)m * HID + n] = (__bf16)(acc[mi][ni][r] + bias_f);
            }
        }
    }
}

// ---------------------------------------------------------------------------
// Flash attention v4 (unchanged since R7; est ~42-48 us): transposed-S data
// flow, shift-free exp2 softmax, double-buffered K/V, one barrier/tile,
// balanced block pairing. grid = 512; block = 256.
// ---------------------------------------------------------------------------
__global__ __launch_bounds__(256)
void attn_flash_mfma_v4(const __bf16* __restrict__ q,
                        const __bf16* __restrict__ k,
                        const __bf16* __restrict__ v,
                        float* __restrict__ out)
{
    __shared__ __align__(16) __bf16 Ks[2][64 * LKV];    // [n][d]
    __shared__ __align__(16) __bf16 Vt[2][64 * LKV];    // [d][n]
    __shared__ __align__(16) __bf16 Ps[4][32 * LP];     // per-wave P [m][n]

    const int tid  = threadIdx.x;
    const int wave = tid >> 6;
    const int lane = tid & 63;
    const int l15  = lane & 15;
    const int quad = lane >> 4;

    const int bx = blockIdx.x;           // 0..511
    const int jj = bx & 7;
    const int bt = ((bx >> 8) & 1) ? jj : 7 - jj;   // pair-balanced LJF
    const int bh = bx >> 3;              // 0..63
    const int h  = bh & (NHEADS - 1);
    const int b  = bh >> 4;
    const int t0 = bt * 128;

    const __bf16* kbase = k + (size_t)b * N_SZ * HID + h * DHEAD;
    const __bf16* vbase = v + (size_t)b * N_SZ * HID + h * DHEAD;

    // ---- Q rows to registers (B-frag of S^T), pre-scaled ----
    bf16x8 qf[2][2];
    {
        const __bf16* qb = q + (size_t)(b * T_SZ + t0 + wave * 32) * HID + h * DHEAD;
#pragma unroll
        for (int g = 0; g < 2; ++g)
#pragma unroll
            for (int kk = 0; kk < 2; ++kk) {
                const bf16x8 raw = *(const bf16x8*)(qb + (size_t)(g * 16 + l15) * HID
                                                    + kk * 32 + quad * 8);
#pragma unroll
                for (int j = 0; j < 8; ++j)
                    qf[g][kk][j] = (__bf16)((float)raw[j] * SM_SCALE_LOG2E);
            }
    }

    const int kr = tid >> 3;
    const int kc = (tid & 7) * 8;
    const int vn = tid & 63;
    const int vd = (tid >> 6) * 8;

#pragma unroll
    for (int p = 0; p < 2; ++p) {
        *(bf16x8*)(&Ks[0][(kr + p * 32) * LKV + kc]) =
            *(const bf16x8*)(kbase + (size_t)(kr + p * 32) * HID + kc);
        const bf16x8 vv = *(const bf16x8*)(vbase + (size_t)vn * HID + vd + p * 32);
#pragma unroll
        for (int j = 0; j < 8; ++j)
            Vt[0][(vd + p * 32 + j) * LKV + vn] = vv[j];
    }
    __syncthreads();

    float lsum[2] = {0.f, 0.f};
    floatx4 oacc[2][4];
#pragma unroll
    for (int g = 0; g < 2; ++g)
#pragma unroll
        for (int nd = 0; nd < 4; ++nd) oacc[g][nd] = (floatx4)(0.0f);

    __bf16* pw = &Ps[wave][0];
    const int ntiles = 2 * bt + 2;

    for (int it = 0; it < ntiles; ++it) {
        const int bi = it & 1;
        const int n0 = it * 64;

        bf16x8 nk0, nk1, nv0, nv1;
        const bool pf = (it + 1 < ntiles);
        if (pf) {
            const int nn0 = n0 + 64;
            nk0 = *(const bf16x8*)(kbase + (size_t)(nn0 + kr) * HID + kc);
            nk1 = *(const bf16x8*)(kbase + (size_t)(nn0 + kr + 32) * HID + kc);
            nv0 = *(const bf16x8*)(vbase + (size_t)(nn0 + vn) * HID + vd);
            nv1 = *(const bf16x8*)(vbase + (size_t)(nn0 + vn) * HID + vd + 32);
        }

        // ---- S^T = K @ Q^T : C/D col=m(l15), row=n(quad*4+r) ----
        floatx4 st[2][4];
#pragma unroll
        for (int g = 0; g < 2; ++g)
#pragma unroll
            for (int ni = 0; ni < 4; ++ni) st[g][ni] = (floatx4)(0.0f);
        const __bf16* ksb = &Ks[bi][0];
#pragma unroll
        for (int kk = 0; kk < 2; ++kk) {
            const int ko = kk * 32 + quad * 8;
#pragma unroll
            for (int ni = 0; ni < 4; ++ni) {
                const bf16x8 af = *(const bf16x8*)(ksb + (ni * 16 + l15) * LKV + ko);
                st[0][ni] = __builtin_amdgcn_mfma_f32_16x16x32_bf16(af, qf[0][kk], st[0][ni], 0, 0, 0);
                st[1][ni] = __builtin_amdgcn_mfma_f32_16x16x32_bf16(af, qf[1][kk], st[1][ni], 0, 0, 0);
            }
        }

        // ---- shift-free softmax; packed b64 P-writes; lane-local lsum ----
        const bool msk = (it >= 2 * bt);
#pragma unroll
        for (int g = 0; g < 2; ++g) {
            const int tq = t0 + wave * 32 + g * 16 + l15;
#pragma unroll
            for (int ni = 0; ni < 4; ++ni) {
                bf16x4 pk;
#pragma unroll
                for (int r = 0; r < 4; ++r) {
                    float p = exp2f(st[g][ni][r]);
                    if (msk) {
                        const int nn = n0 + ni * 16 + quad * 4 + r;
                        p = (nn > tq) ? 0.f : p;
                    }
                    lsum[g] += p;
                    pk[r] = (__bf16)p;
                }
                *(bf16x4*)(pw + (g * 16 + l15) * LP + ni * 16 + quad * 4) = pk;
            }
        }

        // ---- O^T += Vt @ P : C/D col=m(l15), row=d(quad*4+r) ----
        const __bf16* vtb = &Vt[bi][0];
#pragma unroll
        for (int kk = 0; kk < 2; ++kk) {
            const int ko = kk * 32 + quad * 8;
            const bf16x8 bp0 = *(const bf16x8*)(pw + l15 * LP + ko);
            const bf16x8 bp1 = *(const bf16x8*)(pw + (16 + l15) * LP + ko);
#pragma unroll
            for (int nd = 0; nd < 4; ++nd) {
                const bf16x8 av = *(const bf16x8*)(vtb + (nd * 16 + l15) * LKV + ko);
                oacc[0][nd] = __builtin_amdgcn_mfma_f32_16x16x32_bf16(av, bp0, oacc[0][nd], 0, 0, 0);
                oacc[1][nd] = __builtin_amdgcn_mfma_f32_16x16x32_bf16(av, bp1, oacc[1][nd], 0, 0, 0);
            }
        }

        if (pf) {
            const int wb = bi ^ 1;
            *(bf16x8*)(&Ks[wb][kr * LKV + kc]) = nk0;
            *(bf16x8*)(&Ks[wb][(kr + 32) * LKV + kc]) = nk1;
#pragma unroll
            for (int j = 0; j < 8; ++j) {
                Vt[wb][(vd + j) * LKV + vn] = nv0[j];
                Vt[wb][(vd + 32 + j) * LKV + vn] = nv1[j];
            }
        }
        __syncthreads();
    }

    // ---- epilogue ----
#pragma unroll
    for (int g = 0; g < 2; ++g) {
        lsum[g] += __shfl_xor(lsum[g], 16, 64);
        lsum[g] += __shfl_xor(lsum[g], 32, 64);
    }
#pragma unroll
    for (int g = 0; g < 2; ++g) {
        const float invl = 1.0f / lsum[g];
        const int trow = t0 + wave * 32 + g * 16 + l15;
        float* ob = out + (size_t)(b * T_SZ + trow) * HID + h * DHEAD + quad * 4;
#pragma unroll
        for (int nd = 0; nd < 4; ++nd) {
            float4 o4;
            o4.x = oacc[g][nd][0] * invl;
            o4.y = oacc[g][nd][1] * invl;
            o4.z = oacc[g][nd][2] * invl;
            o4.w = oacc[g][nd][3] * invl;
            *(float4*)(ob + nd * 16) = o4;
        }
    }
}

extern "C" void kernel_launch(void* const* d_in, const int* in_sizes, int n_in,
                              void* d_out, int out_size, void* d_ws, size_t ws_size,
                              hipStream_t stream) {
    const float* x   = (const float*)d_in[0];
    const float* enc = (const float*)d_in[1];
    const float* Wq  = (const float*)d_in[2];
    const float* bq  = (const float*)d_in[3];
    const float* Wk  = (const float*)d_in[4];
    const float* bk  = (const float*)d_in[5];
    const float* Wv  = (const float*)d_in[6];
    const float* bv  = (const float*)d_in[7];
    float* out = (float*)d_out;

    char* ws = (char*)d_ws;
    const size_t MiB = 1024 * 1024;
    __bf16* q_ws = (__bf16*)(ws);
    __bf16* k_ws = (__bf16*)(ws + 8 * MiB);
    __bf16* v_ws = (__bf16*)(ws + 16 * MiB);

    const dim3 blk(256);
    gemm3_f32_swz<<<dim3(768), blk, 0, stream>>>(
        x, enc, Wq, Wk, Wv, bq, bk, bv, q_ws, k_ws, v_ws);

    attn_flash_mfma_v4<<<dim3(512), blk, 0, stream>>>(q_ws, k_ws, v_ws, out);
}